// Round 9
// baseline (9214.724 us; speedup 1.0000x reference)
//
#include <hip/hip_runtime.h>

#define B_ 64
#define S_ 512
#define D_ 1024
#define H_ 1024
#define NBLK 256
#define NT 512
#define TB 8      // out-store batch (steps buffered in registers)
#define NSLOT 4   // x->h LDS ring depth (steps of x-wave lead)

typedef __bf16 v8bf __attribute__((ext_vector_type(8)));
typedef float v4f __attribute__((ext_vector_type(4)));
typedef float f32x4 __attribute__((ext_vector_type(4)));
typedef unsigned long long u64;
typedef unsigned u32;

#define MFMA __builtin_amdgcn_mfma_f32_16x16x32_bf16

// Convert 8 consecutive f32 (32B, two float4 loads) to a bf16x8 fragment.
__device__ inline v8bf cvt8(const float* p) {
  f32x4 a = *(const f32x4*)p;
  f32x4 b = *(const f32x4*)(p + 4);
  v8bf r;
  r[0] = (__bf16)a[0]; r[1] = (__bf16)a[1]; r[2] = (__bf16)a[2]; r[3] = (__bf16)a[3];
  r[4] = (__bf16)b[0]; r[5] = (__bf16)b[1]; r[6] = (__bf16)b[2]; r[7] = (__bf16)b[3];
  return r;
}

// Persistent LSTM. ROUND 8 (resubmitted after infra-failed bench): burst
// gather + poll backoff on the r7 skeleton.
// r0-r7 decomposition: the 13us/step is the h-chain's serialized LLC hops.
// Two fixes: (1) the h gather was __hip_atomic_load interleaved with its
// consumer MFMAs -- the compiler cannot burst-issue past consumers, so the
// gather degrades to ~8-16 serialized ~800cy LLC round trips (invariant
// across r0-r7, matching the invariant stall). Replaced with 64 raw
// `global_load_dwordx2 ... sc1` asm loads in two 32-load bursts, each
// drained by ONE explicit s_waitcnt vmcnt(0) + sched_barrier(0) (guide rule
// #18: hipcc hoists register-only MFMAs past inline-asm waitcnt without the
// sched_barrier). Burst 1 flies under burst 0's MFMAs. (2) poll spin was
// ~2.4 TB/s of LLC load traffic (1024 waves x 1KB/iter) queueing ahead of
// the awaited stores -- s_sleep(4) backoff cuts it ~4-8x.
// Kept from r7: x/h wave split (x-waves K 0..1023 feed partials via LDS
// ring, h-waves own the recurrence), per-wave flag systems, no bulk fences,
// vmcnt(0) release, TB=8 batched NT out stores.
__global__ __launch_bounds__(NT, 2)
void lstm_persist(const float* __restrict__ x,    // (B,S,D) f32
                  const float* __restrict__ Wx,   // (4,H,D) f32
                  const float* __restrict__ Wh,   // (4,H,H) f32
                  const float* __restrict__ bias, // (4,H)   f32
                  float* __restrict__ out,        // (B,S,H) ++ (B,H) ++ (B,H), f32
                  __bf16* __restrict__ hblk,      // (2,NBLK,64,4) bf16 blocked h
                  u32* __restrict__ flags)        // [4][NBLK] per-system flags
{
  extern __shared__ char smem[];
  v8bf* wlds = (v8bf*)smem;                    // [16 rows][256 chunks^swz] 64KB
  v4f*  xacc = (v4f*)(smem + 65536);           // [NSLOT][4][64] v4f = 16KB
  u32*  seq  = (u32*)(smem + 65536 + 16384);   // xseq[4*16] ++ hseq[4*16]

  const int tid  = threadIdx.x;
  const int nb   = blockIdx.x;
  const int w8   = tid >> 6;   // 0..7: 0-3 x-waves, 4-7 h-waves
  const int l    = tid & 63;
  const int lm   = l & 15;     // MFMA A-row / B,D-col lane index
  const int quad = l >> 4;     // MFMA k-quad
  const int sw   = lm & 7;     // LDS swizzle key

  // ---- stage weights into LDS (once), f32 -> bf16 (all 8 waves) ----
  for (int i = tid; i < 16 * 256; i += NT) {
    const int nl  = i >> 8;          // 0..15: gate g = nl>>2, local col = nl&3
    const int kc  = i & 255;         // 8-elt chunk index along K (k = kc*8)
    const int g   = nl >> 2;
    const int col = (nb << 2) + (nl & 3);
    const int k   = kc << 3;
    const float* src = (k < D_)
        ? (Wx + ((size_t)(g * H_ + col) * D_ + k))
        : (Wh + ((size_t)(g * H_ + col) * H_ + (k - D_)));
    wlds[(nl << 8) + (kc ^ (nl & 7))] = cvt8(src);
  }
  if (tid < 128) seq[tid] = 0;   // xseq + hseq zeroed

  __syncthreads();  // weights staged + seq init (only barrier in the kernel)

  u32* xseq = seq;        // [w*16] (64B-padded)
  u32* hseq = seq + 64;   // [s*16]

  if (w8 < 4) {
    // ================= x-wave: K 0..1023, no global sync =================
    const int w   = w8;
    const int myb = (w << 4) + lm;
    for (int t = 0; t < S_; ++t) {
      if (t >= NSLOT) {  // slot credit: partner consumed slot from t-NSLOT
        while (__hip_atomic_load(&hseq[w << 4], __ATOMIC_ACQUIRE,
                                 __HIP_MEMORY_SCOPE_WORKGROUP)
               < (u32)(t - NSLOT + 1)) {
          __builtin_amdgcn_s_sleep(2);
        }
      }
      v4f a0 = {0.f,0.f,0.f,0.f}, a1 = {0.f,0.f,0.f,0.f};
      const float* xrow = x + ((size_t)(myb * S_ + t)) * D_ + (quad << 3);
      #pragma unroll 4
      for (int cc = 0; cc < 16; ++cc) {
        const int c0 = cc * 2, c1 = cc * 2 + 1;
        v8bf f0 = cvt8(xrow + (c0 << 5));
        a0 = MFMA(f0, wlds[(lm << 8) + (((c0 << 2) + quad) ^ sw)], a0, 0, 0, 0);
        v8bf f1 = cvt8(xrow + (c1 << 5));
        a1 = MFMA(f1, wlds[(lm << 8) + (((c1 << 2) + quad) ^ sw)], a1, 0, 0, 0);
      }
      xacc[((t & (NSLOT - 1)) << 8) + (w << 6) + l] = a0 + a1;
      asm volatile("s_waitcnt lgkmcnt(0)" ::: "memory");  // ring write landed
      if (l == 0)
        __hip_atomic_store(&xseq[w << 4], (u32)(t + 1), __ATOMIC_RELEASE,
                           __HIP_MEMORY_SCOPE_WORKGROUP);
    }
  } else {
    // ================= h-wave: K 1024..2047 + recurrence =================
    const int s     = w8 & 3;          // wave-system id (= partner x-wave)
    const int myb   = (s << 4) + lm;   // batch row this lane owns
    const int myb4  = myb << 2;
    const int mycol = (nb << 2) + quad;
    float bv[4];
    #pragma unroll
    for (int g = 0; g < 4; ++g) bv[g] = bias[g * H_ + mycol];

    float c_reg = 0.f;
    float obuf[TB];

    const u32* fw     = flags + (s << 8);       // my system's 256 flags
    u32*       myflag = flags + (s << 8) + nb;

    for (int t = 0; t < S_; ++t) {
      // ---- 1. consume partner's x partial (frees ring slot early) ----
      while (__hip_atomic_load(&xseq[s << 4], __ATOMIC_ACQUIRE,
                               __HIP_MEMORY_SCOPE_WORKGROUP) < (u32)(t + 1)) {
        __builtin_amdgcn_s_sleep(2);
      }
      const v4f xa = xacc[((t & (NSLOT - 1)) << 8) + (s << 6) + l];
      asm volatile("s_waitcnt lgkmcnt(0)" ::: "memory");  // xa in registers
      if (l == 0)
        __hip_atomic_store(&hseq[s << 4], (u32)(t + 1), __ATOMIC_RELEASE,
                           __HIP_MEMORY_SCOPE_WORKGROUP);

      v4f acc0 = xa, acc1 = {0.f,0.f,0.f,0.f};

      // ---- 2. wait for my system's 256 producers, then h-GEMM ----
      if (t > 0) {
        const u32 tu = (u32)t;
        for (;;) {  // lane l watches fw[4l..4l+3]; backoff to cut LLC spin
          const u32 f0 = __hip_atomic_load(fw + (l << 2) + 0,
              __ATOMIC_RELAXED, __HIP_MEMORY_SCOPE_AGENT);
          const u32 f1 = __hip_atomic_load(fw + (l << 2) + 1,
              __ATOMIC_RELAXED, __HIP_MEMORY_SCOPE_AGENT);
          const u32 f2 = __hip_atomic_load(fw + (l << 2) + 2,
              __ATOMIC_RELAXED, __HIP_MEMORY_SCOPE_AGENT);
          const u32 f3 = __hip_atomic_load(fw + (l << 2) + 3,
              __ATOMIC_RELAXED, __HIP_MEMORY_SCOPE_AGENT);
          if (__all((f0 >= tu) & (f1 >= tu) & (f2 >= tu) & (f3 >= tu))) break;
          __builtin_amdgcn_s_sleep(4);
        }
        asm volatile("" ::: "memory");  // no hoisting gather above the poll

        // ---- burst gather: 2 x 32 raw sc1 loads, one drain each ----
        // chunk c (c=0..31): k = c*32 + quad*8 -> blocks j0 = 2*quad + 8c,
        // j0+1; 8B each at [block][myb*4]. Burst 1 flies under burst 0's
        // MFMAs. vmcnt(0) (not counted) is deliberately spill-proof.
        const __bf16* hb = hblk + ((t & 1) ? (1 << 16) : 0);
        u64 A0[32], A1[32];
        #pragma unroll
        for (int k = 0; k < 16; ++k) {
          const u64 addr = (u64)(uintptr_t)(hb + (((quad << 1) + (k << 3)) << 8) + myb4);
          asm volatile("global_load_dwordx2 %0, %1, off sc1"
                       : "=v"(A0[2 * k]) : "v"(addr));
          asm volatile("global_load_dwordx2 %0, %1, off offset:512 sc1"
                       : "=v"(A0[2 * k + 1]) : "v"(addr));
        }
        asm volatile("s_waitcnt vmcnt(0)" ::: "memory");
        __builtin_amdgcn_sched_barrier(0);
        #pragma unroll
        for (int k = 0; k < 16; ++k) {
          const u64 addr = (u64)(uintptr_t)(hb + (((quad << 1) + ((k + 16) << 3)) << 8) + myb4);
          asm volatile("global_load_dwordx2 %0, %1, off sc1"
                       : "=v"(A1[2 * k]) : "v"(addr));
          asm volatile("global_load_dwordx2 %0, %1, off offset:512 sc1"
                       : "=v"(A1[2 * k + 1]) : "v"(addr));
        }
        #pragma unroll
        for (int k = 0; k < 16; ++k) {  // consume burst 0 while burst 1 flies
          union { u32 u[4]; v8bf v; } af;
          af.u[0] = (u32)A0[2 * k];     af.u[1] = (u32)(A0[2 * k] >> 32);
          af.u[2] = (u32)A0[2 * k + 1]; af.u[3] = (u32)(A0[2 * k + 1] >> 32);
          v8bf bf = wlds[(lm << 8) + ((128 + (k << 2) + quad) ^ sw)];
          if (k & 1) acc1 = MFMA(af.v, bf, acc1, 0, 0, 0);
          else       acc0 = MFMA(af.v, bf, acc0, 0, 0, 0);
        }
        asm volatile("s_waitcnt vmcnt(0)" ::: "memory");
        __builtin_amdgcn_sched_barrier(0);
        #pragma unroll
        for (int k = 0; k < 16; ++k) {
          const int c = k + 16;
          union { u32 u[4]; v8bf v; } af;
          af.u[0] = (u32)A1[2 * k];     af.u[1] = (u32)(A1[2 * k] >> 32);
          af.u[2] = (u32)A1[2 * k + 1]; af.u[3] = (u32)(A1[2 * k + 1] >> 32);
          v8bf bf = wlds[(lm << 8) + ((128 + (c << 2) + quad) ^ sw)];
          if (c & 1) acc1 = MFMA(af.v, bf, acc1, 0, 0, 0);
          else       acc0 = MFMA(af.v, bf, acc0, 0, 0, 0);
        }
      }

      v4f accs = acc0 + acc1;

      // ---- gate exchange: D layout row m=quad*4+r (batch), col n=lm.
      // Dest lane (b=16s+lm, c=quad) needs cols {g*4+quad} at row lm. ----
      float gv[4];
      const int rsel = lm & 3;
      #pragma unroll
      for (int g = 0; g < 4; ++g) {
        const int srcl = ((lm >> 2) << 4) + (g << 2) + quad;
        float t0 = __shfl(accs[0], srcl, 64);
        float t1 = __shfl(accs[1], srcl, 64);
        float t2 = __shfl(accs[2], srcl, 64);
        float t3 = __shfl(accs[3], srcl, 64);
        gv[g] = (rsel == 0 ? t0 : rsel == 1 ? t1 : rsel == 2 ? t2 : t3) + bv[g];
      }

      // ---- LSTM pointwise (fp32) ----
      const float it = 1.f / (1.f + __expf(-gv[0]));
      const float ft = 1.f / (1.f + __expf(-gv[1]));
      const float ot = 1.f / (1.f + __expf(-gv[2]));
      const float ch = 1.f - 2.f / (__expf(2.f * gv[3]) + 1.f);  // tanh
      c_reg = ft * c_reg + it * ch;
      const float hn = ot * (1.f - 2.f / (__expf(2.f * c_reg) + 1.f));

      // ---- blocked h store (r5): wave writes 128B contiguous ----
      {
        union { __bf16 b; unsigned short u; } hb2;
        hb2.b = (__bf16)hn;
        __hip_atomic_store(
            (unsigned short*)(hblk + (((t + 1) & 1) ? (1 << 16) : 0)
                              + (nb << 8) + myb4 + quad),
            hb2.u, __ATOMIC_RELAXED, __HIP_MEMORY_SCOPE_AGENT);
      }

      // ---- per-wave release: drain MY stores only, then arrive ----
      asm volatile("s_waitcnt vmcnt(0)" ::: "memory");
      __hip_atomic_store(myflag, (u32)(t + 1), __ATOMIC_RELAXED,
                         __HIP_MEMORY_SCOPE_AGENT);

      // ---- batched out stores (after the release; ~TB steps to drain) ----
      obuf[t & (TB - 1)] = hn;
      if ((t & (TB - 1)) == TB - 1) {
        #pragma unroll
        for (int i = 0; i < TB; ++i)
          __builtin_nontemporal_store(
              obuf[i], &out[((size_t)(myb * S_ + (t - TB + 1 + i))) * H_ + mycol]);
      }
      if (t == S_ - 1) {
        __builtin_nontemporal_store(
            hn, &out[(size_t)B_ * S_ * H_ + (size_t)myb * H_ + mycol]);   // h_last
        __builtin_nontemporal_store(
            c_reg, &out[(size_t)B_ * S_ * H_ + (size_t)(B_ * H_)
                        + (size_t)myb * H_ + mycol]);                      // c_last
      }
    }
  }
}

extern "C" void kernel_launch(void* const* d_in, const int* in_sizes, int n_in,
                              void* d_out, int out_size, void* d_ws, size_t ws_size,
                              hipStream_t stream) {
  const float* x    = (const float*)d_in[0];
  const float* Wx   = (const float*)d_in[1];
  const float* Wh   = (const float*)d_in[2];
  const float* bias = (const float*)d_in[3];
  float* out = (float*)d_out;

  u32*    flags = (u32*)d_ws;                    // 4*NBLK*4B = 4KB region
  __bf16* hblk  = (__bf16*)((char*)d_ws + 4096); // 2*256*256 bf16 = 256KB

  // ws is poisoned 0xAA before every timed launch: zero the flag region.
  hipMemsetAsync(d_ws, 0, 4096, stream);

  const size_t lds_bytes = 65536 + NSLOT * 4 * 64 * 16 + 512;  // 82432
  lstm_persist<<<dim3(NBLK), dim3(NT), lds_bytes, stream>>>(
      x, Wx, Wh, bias, out, hblk, flags);
}

// Round 11
// 7528.620 us; speedup vs baseline: 1.2240x; 1.2240x over previous
//
#include <hip/hip_runtime.h>

#define B_ 64
#define S_ 512
#define D_ 1024
#define H_ 1024
#define NBLK 256
#define NT 512
#define TB 8      // out-store batch (steps buffered in registers)
#define NSLOT 4   // x->h LDS ring depth (steps of x-wave lead)

typedef __bf16 v8bf __attribute__((ext_vector_type(8)));
typedef float v4f __attribute__((ext_vector_type(4)));
typedef float f32x4 __attribute__((ext_vector_type(4)));
typedef unsigned uint32;
typedef unsigned long long u64;
typedef unsigned uint32x4 __attribute__((ext_vector_type(4)));

#define MFMA __builtin_amdgcn_mfma_f32_16x16x32_bf16

// Convert 8 consecutive f32 (32B, two float4 loads) to a bf16x8 fragment.
__device__ inline v8bf cvt8(const float* p) {
  f32x4 a = *(const f32x4*)p;
  f32x4 b = *(const f32x4*)(p + 4);
  v8bf r;
  r[0] = (__bf16)a[0]; r[1] = (__bf16)a[1]; r[2] = (__bf16)a[2]; r[3] = (__bf16)a[3];
  r[4] = (__bf16)b[0]; r[5] = (__bf16)b[1]; r[6] = (__bf16)b[2]; r[7] = (__bf16)b[3];
  return r;
}

// Persistent LSTM. ROUND 10 (resubmitted: removed an invalid leftover
// typedef that broke compilation; zero functional changes).
// SELF-CERTIFYING h exchange (tag-in-payload).
// r9's burst-gather regression priced one LLC/MALL RTT at ~2.5-3us; r7's
// 13.1us/step == ~4-5 serial RTTs (h-store ack -> flag visibility -> poll
// detect -> gather), invariant across every protocol variant r0-r9 because
// all kept 4 hops. This round removes hops, not latency:
//  - h word = (bf16(h)<<16) | (t+1): payload + step tag in ONE u32 store.
//    Producer: single relaxed sc1 store. NO vmcnt drain, NO flag. (-2 hops)
//  - Consumer: gather the data itself, retry until all embedded tags == t.
//    Detection and fetch share the same RTT. (-1 hop)  Chain = 2 RTTs.
//  - WAR without flags: producer stores tag t+2 only after its step-t+1
//    gather saw tag t+1 from ALL blocks, which (data dep: gather->MFMA->
//    h->store) implies every block finished reading the buffer being
//    overwritten. Double-buffer suffices. 0xAA poison (tag 0xAAAA not in
//    [1,512]) reads as stale -> no memset needed.
//  - Gather pipelined in 4 groups of 8 chunks: counted vmcnt(16) +
//    sched_barrier(0) so only group 0's RTT is exposed. Retry refetches
//    only the stale group (vmcnt(0) drain, rare).
//  - Numerics identical to r7 (bf16 h feedback extracted from high u16).
// Kept from r7: x/h wave split (x-waves K 0..1023 feed partials via LDS
// ring), TB=8 batched NT out stores, s_sleep(1) backoffs.
__global__ __launch_bounds__(NT, 2)
void lstm_persist(const float* __restrict__ x,    // (B,S,D) f32
                  const float* __restrict__ Wx,   // (4,H,D) f32
                  const float* __restrict__ Wh,   // (4,H,H) f32
                  const float* __restrict__ bias, // (4,H)   f32
                  float* __restrict__ out,        // (B,S,H) ++ (B,H) ++ (B,H), f32
                  uint32* __restrict__ hblk)      // (2,NBLK,64,4) u32 tagged h
{
  extern __shared__ char smem[];
  v8bf*   wlds = (v8bf*)smem;                  // [16 rows][256 chunks^swz] 64KB
  v4f*    xacc = (v4f*)(smem + 65536);         // [NSLOT][4][64] v4f = 16KB
  uint32* seq  = (uint32*)(smem + 65536 + 16384); // xseq[4*16] ++ hseq[4*16]

  const int tid  = threadIdx.x;
  const int nb   = blockIdx.x;
  const int w8   = tid >> 6;   // 0..7: 0-3 x-waves, 4-7 h-waves
  const int l    = tid & 63;
  const int lm   = l & 15;     // MFMA A-row / B,D-col lane index
  const int quad = l >> 4;     // MFMA k-quad
  const int sw   = lm & 7;     // LDS swizzle key

  // ---- stage weights into LDS (once), f32 -> bf16 (all 8 waves) ----
  for (int i = tid; i < 16 * 256; i += NT) {
    const int nl  = i >> 8;          // 0..15: gate g = nl>>2, local col = nl&3
    const int kc  = i & 255;         // 8-elt chunk index along K (k = kc*8)
    const int g   = nl >> 2;
    const int col = (nb << 2) + (nl & 3);
    const int k   = kc << 3;
    const float* src = (k < D_)
        ? (Wx + ((size_t)(g * H_ + col) * D_ + k))
        : (Wh + ((size_t)(g * H_ + col) * H_ + (k - D_)));
    wlds[(nl << 8) + (kc ^ (nl & 7))] = cvt8(src);
  }
  if (tid < 128) seq[tid] = 0;   // xseq + hseq zeroed

  __syncthreads();  // weights staged + seq init (only barrier in the kernel)

  uint32* xseq = seq;        // [w*16] (64B-padded)
  uint32* hseq = seq + 64;   // [s*16]

  if (w8 < 4) {
    // ================= x-wave: K 0..1023, no global sync =================
    const int w   = w8;
    const int myb = (w << 4) + lm;
    for (int t = 0; t < S_; ++t) {
      if (t >= NSLOT) {  // slot credit: partner consumed slot from t-NSLOT
        while (__hip_atomic_load(&hseq[w << 4], __ATOMIC_ACQUIRE,
                                 __HIP_MEMORY_SCOPE_WORKGROUP)
               < (uint32)(t - NSLOT + 1)) {
          __builtin_amdgcn_s_sleep(1);
        }
      }
      v4f a0 = {0.f,0.f,0.f,0.f}, a1 = {0.f,0.f,0.f,0.f};
      const float* xrow = x + ((size_t)(myb * S_ + t)) * D_ + (quad << 3);
      #pragma unroll 4
      for (int cc = 0; cc < 16; ++cc) {
        const int c0 = cc * 2, c1 = cc * 2 + 1;
        v8bf f0 = cvt8(xrow + (c0 << 5));
        a0 = MFMA(f0, wlds[(lm << 8) + (((c0 << 2) + quad) ^ sw)], a0, 0, 0, 0);
        v8bf f1 = cvt8(xrow + (c1 << 5));
        a1 = MFMA(f1, wlds[(lm << 8) + (((c1 << 2) + quad) ^ sw)], a1, 0, 0, 0);
      }
      xacc[((t & (NSLOT - 1)) << 8) + (w << 6) + l] = a0 + a1;
      asm volatile("s_waitcnt lgkmcnt(0)" ::: "memory");  // ring write landed
      if (l == 0)
        __hip_atomic_store(&xseq[w << 4], (uint32)(t + 1), __ATOMIC_RELEASE,
                           __HIP_MEMORY_SCOPE_WORKGROUP);
    }
  } else {
    // ================= h-wave: K 1024..2047 + recurrence =================
    const int s     = w8 & 3;          // wave-system id (= partner x-wave)
    const int myb   = (s << 4) + lm;   // batch row this lane owns
    const int mycol = (nb << 2) + quad;
    float bv[4];
    #pragma unroll
    for (int g = 0; g < 4; ++g) bv[g] = bias[g * H_ + mycol];

    float c_reg = 0.f;
    float obuf[TB];
    v4f acc0, acc1;

// issue one group (8 chunks = 16 dwordx4) of the tagged-h gather.
// chunk c = g*8+cc: word offset = c*2048 + quad*512 + myb*4 -> bytes
// g*65536 + cc*8192 + (lane base quad*2048 + myb*16). Tile pair at +0/+1024.
#define ISSUE_GRP(Rn, g)                                                      \
  {                                                                           \
    const char* gb = hbase + ((g) << 16);                                     \
    _Pragma("unroll")                                                         \
    for (int cc = 0; cc < 8; ++cc) {                                          \
      u64 a_ = (u64)(uintptr_t)(gb + (cc << 13));                             \
      asm volatile("global_load_dwordx4 %0, %2, off sc1\n\t"                  \
                   "global_load_dwordx4 %1, %2, off offset:1024 sc1"          \
                   : "=&v"(Rn[2 * cc]), "=&v"(Rn[2 * cc + 1])                 \
                   : "v"(a_) : "memory");                                     \
    }                                                                         \
  }

// check all 64 embedded tags of a group; on stale, refetch the group (rare).
// then convert high-u16 bf16 payloads (v_perm) and run 16 MFMAs.
#define CHECK_CONSUME(Rn, g)                                                  \
  {                                                                           \
    for (;;) {                                                                \
      int ok = 1;                                                             \
      _Pragma("unroll")                                                       \
      for (int i = 0; i < 16; ++i) {                                          \
        ok &= ((Rn[i][0] & 0xFFFFu) == tu);                                   \
        ok &= ((Rn[i][1] & 0xFFFFu) == tu);                                   \
        ok &= ((Rn[i][2] & 0xFFFFu) == tu);                                   \
        ok &= ((Rn[i][3] & 0xFFFFu) == tu);                                   \
      }                                                                       \
      if (__all(ok)) break;                                                   \
      __builtin_amdgcn_s_sleep(1);                                            \
      ISSUE_GRP(Rn, g);                                                       \
      asm volatile("s_waitcnt vmcnt(0)" ::: "memory");                        \
      __builtin_amdgcn_sched_barrier(0);                                      \
    }                                                                         \
    _Pragma("unroll")                                                         \
    for (int cc = 0; cc < 8; ++cc) {                                          \
      const int c_ = (g) * 8 + cc;                                            \
      union { uint32 u[4]; v8bf v; } A_;                                      \
      A_.u[0] = __builtin_amdgcn_perm(Rn[2 * cc][1], Rn[2 * cc][0], 0x07060302u); \
      A_.u[1] = __builtin_amdgcn_perm(Rn[2 * cc][3], Rn[2 * cc][2], 0x07060302u); \
      A_.u[2] = __builtin_amdgcn_perm(Rn[2 * cc + 1][1], Rn[2 * cc + 1][0], 0x07060302u); \
      A_.u[3] = __builtin_amdgcn_perm(Rn[2 * cc + 1][3], Rn[2 * cc + 1][2], 0x07060302u); \
      v8bf bf_ = wlds[(lm << 8) + ((128 + (c_ << 2) + quad) ^ sw)];           \
      if (cc & 1) acc1 = MFMA(A_.v, bf_, acc1, 0, 0, 0);                      \
      else        acc0 = MFMA(A_.v, bf_, acc0, 0, 0, 0);                      \
    }                                                                         \
  }

    for (int t = 0; t < S_; ++t) {
      // ---- 1. consume partner's x partial (frees ring slot early) ----
      while (__hip_atomic_load(&xseq[s << 4], __ATOMIC_ACQUIRE,
                               __HIP_MEMORY_SCOPE_WORKGROUP) < (uint32)(t + 1)) {
        __builtin_amdgcn_s_sleep(1);
      }
      const v4f xa = xacc[((t & (NSLOT - 1)) << 8) + (s << 6) + l];
      asm volatile("s_waitcnt lgkmcnt(0)" ::: "memory");  // xa in registers
      if (l == 0)
        __hip_atomic_store(&hseq[s << 4], (uint32)(t + 1), __ATOMIC_RELEASE,
                           __HIP_MEMORY_SCOPE_WORKGROUP);

      acc0 = xa;
      acc1 = (v4f){0.f, 0.f, 0.f, 0.f};

      // ---- 2. tagged gather + h-GEMM (pipelined, tags == t certify) ----
      if (t > 0) {
        const uint32 tu = (uint32)t;
        const char* hbase = (const char*)(hblk + ((t & 1) ? 65536 : 0))
                            + (quad << 11) + (myb << 4);
        uint32x4 R0[16], R1[16];
        ISSUE_GRP(R0, 0);
        ISSUE_GRP(R1, 1);
        asm volatile("s_waitcnt vmcnt(16)" ::: "memory");
        __builtin_amdgcn_sched_barrier(0);
        CHECK_CONSUME(R0, 0);
        ISSUE_GRP(R0, 2);
        asm volatile("s_waitcnt vmcnt(16)" ::: "memory");
        __builtin_amdgcn_sched_barrier(0);
        CHECK_CONSUME(R1, 1);
        ISSUE_GRP(R1, 3);
        asm volatile("s_waitcnt vmcnt(16)" ::: "memory");
        __builtin_amdgcn_sched_barrier(0);
        CHECK_CONSUME(R0, 2);
        asm volatile("s_waitcnt vmcnt(0)" ::: "memory");
        __builtin_amdgcn_sched_barrier(0);
        CHECK_CONSUME(R1, 3);
      }

      v4f accs = acc0 + acc1;

      // ---- gate exchange: D layout row m=quad*4+r (batch), col n=lm.
      // Dest lane (b=16s+lm, c=quad) needs cols {g*4+quad} at row lm. ----
      float gv[4];
      const int rsel = lm & 3;
      #pragma unroll
      for (int g = 0; g < 4; ++g) {
        const int srcl = ((lm >> 2) << 4) + (g << 2) + quad;
        float t0 = __shfl(accs[0], srcl, 64);
        float t1 = __shfl(accs[1], srcl, 64);
        float t2 = __shfl(accs[2], srcl, 64);
        float t3 = __shfl(accs[3], srcl, 64);
        gv[g] = (rsel == 0 ? t0 : rsel == 1 ? t1 : rsel == 2 ? t2 : t3) + bv[g];
      }

      // ---- LSTM pointwise (fp32) ----
      const float it = 1.f / (1.f + __expf(-gv[0]));
      const float ft = 1.f / (1.f + __expf(-gv[1]));
      const float ot = 1.f / (1.f + __expf(-gv[2]));
      const float ch = 1.f - 2.f / (__expf(2.f * gv[3]) + 1.f);  // tanh
      c_reg = ft * c_reg + it * ch;
      const float hn = ot * (1.f - 2.f / (__expf(2.f * c_reg) + 1.f));

      // ---- self-certifying h store: payload+tag in ONE u32, no drain,
      // no flag. Consumers poll the data itself. ----
      {
        union { __bf16 b; unsigned short u; } hb2;
        hb2.b = (__bf16)hn;
        const uint32 word = ((uint32)hb2.u << 16) | (uint32)(t + 1);
        __hip_atomic_store(hblk + (((t + 1) & 1) ? 65536 : 0)
                           + (nb << 8) + (myb << 2) + quad,
                           word, __ATOMIC_RELAXED, __HIP_MEMORY_SCOPE_AGENT);
      }

      // ---- batched out stores (off the critical path) ----
      obuf[t & (TB - 1)] = hn;
      if ((t & (TB - 1)) == TB - 1) {
        #pragma unroll
        for (int i = 0; i < TB; ++i)
          __builtin_nontemporal_store(
              obuf[i], &out[((size_t)(myb * S_ + (t - TB + 1 + i))) * H_ + mycol]);
      }
      if (t == S_ - 1) {
        __builtin_nontemporal_store(
            hn, &out[(size_t)B_ * S_ * H_ + (size_t)myb * H_ + mycol]);   // h_last
        __builtin_nontemporal_store(
            c_reg, &out[(size_t)B_ * S_ * H_ + (size_t)(B_ * H_)
                        + (size_t)myb * H_ + mycol]);                      // c_last
      }
    }
#undef ISSUE_GRP
#undef CHECK_CONSUME
  }
}

extern "C" void kernel_launch(void* const* d_in, const int* in_sizes, int n_in,
                              void* d_out, int out_size, void* d_ws, size_t ws_size,
                              hipStream_t stream) {
  const float* x    = (const float*)d_in[0];
  const float* Wx   = (const float*)d_in[1];
  const float* Wh   = (const float*)d_in[2];
  const float* bias = (const float*)d_in[3];
  float* out = (float*)d_out;

  // hblk: 2 bufs x 256 tiles x 256 u32 words = 512KB of ws. No memset
  // needed: 0xAA poison gives tag 0xAAAA which never matches t in [1,512),
  // so poisoned words read as stale and consumers retry until real data.
  uint32* hblk = (uint32*)d_ws;

  const size_t lds_bytes = 65536 + NSLOT * 4 * 64 * 16 + 512;  // 82432
  lstm_persist<<<dim3(NBLK), dim3(NT), lds_bytes, stream>>>(
      x, Wx, Wh, bias, out, hblk);
}